// Round 1
// baseline (929.101 us; speedup 1.0000x reference)
//
#include <hip/hip_runtime.h>

#define NN 50000
#define NE 800000
#define INC 32
#define HH 64
#define H2 128
#define OC 16
#define ON 17
#define NL 4
#define MEPS 1e-7f
#define LNE 1e-5f
#define SCAN_BLOCKS 196   /* ceil(50000/256) */

// ---------- ordered-uint encoding for float atomic max ----------
__device__ __forceinline__ unsigned fenc(float x) {
    unsigned u = __float_as_uint(x);
    return (u & 0x80000000u) ? ~u : (u | 0x80000000u);
}
__device__ __forceinline__ float fdec(unsigned u) {
    return (u & 0x80000000u) ? __uint_as_float(u & 0x7fffffffu)
                             : __uint_as_float(~u);
}

// ---------- CSR build ----------
__global__ __launch_bounds__(256) void k_hist(const int* __restrict__ dst, int* __restrict__ counts) {
    int e = blockIdx.x * 256 + threadIdx.x;
    if (e < NE) atomicAdd(&counts[dst[e]], 1);
}

__global__ __launch_bounds__(256) void k_scan1(const int* __restrict__ counts,
                                               int* __restrict__ incl, int* __restrict__ bsums) {
    __shared__ int s[256];
    int t = threadIdx.x;
    int i = blockIdx.x * 256 + t;
    int v = (i < NN) ? counts[i] : 0;
    s[t] = v;
    __syncthreads();
    for (int off = 1; off < 256; off <<= 1) {
        int x = (t >= off) ? s[t - off] : 0;
        __syncthreads();
        s[t] += x;
        __syncthreads();
    }
    if (i < NN) incl[i] = s[t];
    if (t == 255) bsums[blockIdx.x] = s[255];
}

__global__ __launch_bounds__(256) void k_scan2(int* __restrict__ bsums) {
    __shared__ int s[256];
    int t = threadIdx.x;
    int v = (t < SCAN_BLOCKS) ? bsums[t] : 0;
    s[t] = v;
    __syncthreads();
    for (int off = 1; off < 256; off <<= 1) {
        int x = (t >= off) ? s[t - off] : 0;
        __syncthreads();
        s[t] += x;
        __syncthreads();
    }
    if (t < SCAN_BLOCKS) bsums[t] = s[t] - v;  // exclusive
}

__global__ __launch_bounds__(256) void k_scan3(const int* __restrict__ counts,
                                               int* __restrict__ rowst, const int* __restrict__ bsums) {
    int i = blockIdx.x * 256 + threadIdx.x;
    if (i < NN) rowst[i] = rowst[i] - counts[i] + bsums[blockIdx.x];
}

__global__ __launch_bounds__(256) void k_scatter(const int* __restrict__ src, const int* __restrict__ dst,
                                                 const int* __restrict__ rowst, int* __restrict__ cursor,
                                                 int* __restrict__ ssrc) {
    int e = blockIdx.x * 256 + threadIdx.x;
    if (e < NE) {
        int d = dst[e];
        int pos = rowst[d] + atomicAdd(&cursor[d], 1);
        ssrc[pos] = src[e];
    }
}

// ---------- node encoder: h = x @ W + b  ([N,32]@[32,64]) ----------
__global__ __launch_bounds__(256) void k_encoder(const float* __restrict__ x, const float* __restrict__ W,
                                                 const float* __restrict__ b, float* __restrict__ h) {
    __shared__ float Ws[INC * HH];
    __shared__ float bs[HH];
    int tid = threadIdx.x;
    for (int i = tid; i < INC * HH; i += 256) Ws[i] = W[i];
    if (tid < HH) bs[tid] = b[tid];
    __syncthreads();
    int wid = tid >> 6, lane = tid & 63;
    int n = blockIdx.x * 4 + wid;
    if (n >= NN) return;
    float v = (lane < INC) ? x[(size_t)n * INC + lane] : 0.f;
    float acc = bs[lane];
    #pragma unroll
    for (int k = 0; k < INC; ++k)
        acc += __shfl(v, k) * Ws[k * HH + lane];
    h[(size_t)n * HH + lane] = acc;
}

// ---------- y = relu(LayerNorm(h))  (wave per node) ----------
__global__ __launch_bounds__(256) void k_lnrelu(const float* __restrict__ h, const float* __restrict__ g,
                                                const float* __restrict__ b, float* __restrict__ y) {
    int tid = threadIdx.x;
    int wid = tid >> 6, lane = tid & 63;
    int n = blockIdx.x * 4 + wid;
    if (n >= NN) return;
    float v = h[(size_t)n * HH + lane];
    float s = v;
    #pragma unroll
    for (int m = 1; m < 64; m <<= 1) s += __shfl_xor(s, m);
    float mu = s * (1.f / 64.f);
    float d = v - mu;
    float q = d * d;
    #pragma unroll
    for (int m = 1; m < 64; m <<= 1) q += __shfl_xor(q, m);
    float rs = rsqrtf(q * (1.f / 64.f) + LNE);
    float r = d * rs * g[lane] + b[lane];
    y[(size_t)n * HH + lane] = fmaxf(r, 0.f);
}

// ---------- per-dst softmax aggregation (online softmax, wave per node) ----------
__global__ __launch_bounds__(256) void k_agg(const float* __restrict__ y, const int* __restrict__ rowst,
                                             const int* __restrict__ counts, const int* __restrict__ ssrc,
                                             const float* __restrict__ tp, float* __restrict__ ag) {
    int tid = threadIdx.x;
    int wid = tid >> 6, lane = tid & 63;
    int n = blockIdx.x * 4 + wid;
    if (n >= NN) return;
    float tval = *tp;
    int start = rowst[n];
    int deg = counts[n];
    float M = -INFINITY, Sa = 0.f, Sma = 0.f;
    for (int e = 0; e < deg; ++e) {
        int s = ssrc[start + e];
        float v = y[(size_t)s * HH + lane];
        float m = fmaxf(v, 0.f) + MEPS;
        float z = tval * m;
        float zm = fmaxf(M, z);
        float corr = __expf(M - zm);   // 0 when M=-inf
        float a = __expf(z - zm);
        Sa = Sa * corr + a;
        Sma = Sma * corr + m * a;
        M = zm;
    }
    float agg = Sma / fmaxf(Sa, MEPS);  // deg==0 -> 0/eps = 0
    ag[(size_t)n * HH + lane] = agg + y[(size_t)n * HH + lane];
}

// ---------- GEMM A: U = ag @ W1 + b1  ([N,64]@[64,128]) ----------
__global__ __launch_bounds__(256) void k_gemmA(const float* __restrict__ A, const float* __restrict__ W,
                                               const float* __restrict__ bias, float* __restrict__ U) {
    __shared__ float As[64 * 68];     // pad 4 -> 2-way conflicts only (free)
    __shared__ float Bs[HH * H2];     // 8192
    __shared__ float bb[H2];
    int tid = threadIdx.x;
    int nb = blockIdx.x * 64;
    for (int i = tid; i < HH * H2 / 4; i += 256)
        ((float4*)Bs)[i] = ((const float4*)W)[i];
    if (tid < H2) bb[tid] = bias[tid];
    {
        int row = tid >> 2, cb = (tid & 3) * 16;
        int n = nb + row;
        float4* dp = (float4*)(As + row * 68 + cb);
        if (n < NN) {
            const float4* sp = (const float4*)(A + (size_t)n * HH + cb);
            #pragma unroll
            for (int i = 0; i < 4; ++i) dp[i] = sp[i];
        } else {
            float4 z = {0.f, 0.f, 0.f, 0.f};
            #pragma unroll
            for (int i = 0; i < 4; ++i) dp[i] = z;
        }
    }
    __syncthreads();
    int tx = tid & 15, ty = tid >> 4;
    int r0 = ty * 4, j0 = tx * 8;
    float acc[4][8] = {};
    #pragma unroll 8
    for (int k = 0; k < HH; ++k) {
        float4 b0 = *(const float4*)(Bs + k * H2 + j0);
        float4 b1 = *(const float4*)(Bs + k * H2 + j0 + 4);
        #pragma unroll
        for (int r = 0; r < 4; ++r) {
            float a = As[(r0 + r) * 68 + k];
            acc[r][0] += a * b0.x; acc[r][1] += a * b0.y;
            acc[r][2] += a * b0.z; acc[r][3] += a * b0.w;
            acc[r][4] += a * b1.x; acc[r][5] += a * b1.y;
            acc[r][6] += a * b1.z; acc[r][7] += a * b1.w;
        }
    }
    #pragma unroll
    for (int r = 0; r < 4; ++r) {
        int n = nb + r0 + r;
        if (n < NN) {
            float4 o0, o1;
            o0.x = acc[r][0] + bb[j0];     o0.y = acc[r][1] + bb[j0 + 1];
            o0.z = acc[r][2] + bb[j0 + 2]; o0.w = acc[r][3] + bb[j0 + 3];
            o1.x = acc[r][4] + bb[j0 + 4]; o1.y = acc[r][5] + bb[j0 + 5];
            o1.z = acc[r][6] + bb[j0 + 6]; o1.w = acc[r][7] + bb[j0 + 7];
            *(float4*)(U + (size_t)n * H2 + j0) = o0;
            *(float4*)(U + (size_t)n * H2 + j0 + 4) = o1;
        }
    }
}

// ---------- GEMM B with fused LN(128)+ReLU on input tile, +bias, +optional residual ----------
__global__ __launch_bounds__(256) void k_gemmB(const float* __restrict__ U, const float* __restrict__ W,
                                               const float* __restrict__ bias,
                                               const float* __restrict__ lng, const float* __restrict__ lnb,
                                               const float* __restrict__ hres, float* __restrict__ hout) {
    __shared__ float As[64 * 132];    // pad 4
    __shared__ float Bs[H2 * HH];     // 8192
    __shared__ float bb[HH];
    __shared__ float lg[H2], lb[H2];
    __shared__ float ps[64 * 4], psq[64 * 4];
    __shared__ float mus[64], rss[64];
    int tid = threadIdx.x;
    int nb = blockIdx.x * 64;
    for (int i = tid; i < H2 * HH / 4; i += 256)
        ((float4*)Bs)[i] = ((const float4*)W)[i];
    if (tid < HH) bb[tid] = bias[tid];
    if (tid < H2) { lg[tid] = lng[tid]; lb[tid] = lnb[tid]; }
    {
        int row = tid >> 2, cb = (tid & 3) * 32;
        int n = nb + row;
        float4* dp = (float4*)(As + row * 132 + cb);
        if (n < NN) {
            const float4* sp = (const float4*)(U + (size_t)n * H2 + cb);
            #pragma unroll
            for (int i = 0; i < 8; ++i) dp[i] = sp[i];
        } else {
            float4 z = {0.f, 0.f, 0.f, 0.f};
            #pragma unroll
            for (int i = 0; i < 8; ++i) dp[i] = z;
        }
    }
    __syncthreads();
    // LN stats: thread (row, q) handles cols {q, q+4, q+8, ...} (bank-spread)
    {
        int row = tid >> 2, q = tid & 3;
        const float* rp = As + row * 132;
        float s = 0.f, sq = 0.f;
        #pragma unroll
        for (int i = 0; i < 32; ++i) { float v = rp[i * 4 + q]; s += v; sq += v * v; }
        ps[row * 4 + q] = s; psq[row * 4 + q] = sq;
    }
    __syncthreads();
    if (tid < 64) {
        float s = ps[tid * 4] + ps[tid * 4 + 1] + ps[tid * 4 + 2] + ps[tid * 4 + 3];
        float sq = psq[tid * 4] + psq[tid * 4 + 1] + psq[tid * 4 + 2] + psq[tid * 4 + 3];
        float mu = s * (1.f / 128.f);
        float var = sq * (1.f / 128.f) - mu * mu;
        mus[tid] = mu;
        rss[tid] = rsqrtf(fmaxf(var, 0.f) + LNE);
    }
    __syncthreads();
    {
        int row = tid >> 2, q = tid & 3;
        float mu = mus[row], rs = rss[row];
        float* rp = As + row * 132;
        #pragma unroll
        for (int i = 0; i < 32; ++i) {
            int c = i * 4 + q;
            float v = (rp[c] - mu) * rs * lg[c] + lb[c];
            rp[c] = fmaxf(v, 0.f);
        }
    }
    __syncthreads();
    int tx = tid & 15, ty = tid >> 4;
    int r0 = ty * 4, o0 = tx * 4;
    float acc[4][4] = {};
    #pragma unroll 8
    for (int k = 0; k < H2; ++k) {
        float4 b4 = *(const float4*)(Bs + k * HH + o0);
        #pragma unroll
        for (int r = 0; r < 4; ++r) {
            float a = As[(r0 + r) * 132 + k];
            acc[r][0] += a * b4.x; acc[r][1] += a * b4.y;
            acc[r][2] += a * b4.z; acc[r][3] += a * b4.w;
        }
    }
    #pragma unroll
    for (int r = 0; r < 4; ++r) {
        int n = nb + r0 + r;
        if (n < NN) {
            float4 o;
            o.x = acc[r][0] + bb[o0];     o.y = acc[r][1] + bb[o0 + 1];
            o.z = acc[r][2] + bb[o0 + 2]; o.w = acc[r][3] + bb[o0 + 3];
            if (hres) {
                float4 hr = *(const float4*)(hres + (size_t)n * HH + o0);
                o.x += hr.x; o.y += hr.y; o.z += hr.z; o.w += hr.w;
            }
            *(float4*)(hout + (size_t)n * HH + o0) = o;
        }
    }
}

// ---------- output heads ----------
__global__ __launch_bounds__(256) void k_out(const float* __restrict__ y,
                                             const float* __restrict__ gW, const float* __restrict__ gb,
                                             const float* __restrict__ nW, const float* __restrict__ nbp,
                                             float* __restrict__ dout, unsigned* __restrict__ genc) {
    __shared__ float gWs[HH * OC];
    __shared__ float nWs[HH * ON];
    __shared__ float gbs[OC], nbs[ON];
    int tid = threadIdx.x;
    for (int i = tid; i < HH * OC; i += 256) gWs[i] = gW[i];
    for (int i = tid; i < HH * ON; i += 256) nWs[i] = nW[i];
    if (tid < OC) gbs[tid] = gb[tid];
    if (tid < ON) nbs[tid] = nbp[tid];
    __syncthreads();
    int n = blockIdx.x * 256 + tid;
    float accn[ON], accg[OC];
    #pragma unroll
    for (int j = 0; j < ON; ++j) accn[j] = nbs[j];
    #pragma unroll
    for (int j = 0; j < OC; ++j) accg[j] = gbs[j];
    if (n < NN) {
        const float* yp = y + (size_t)n * HH;
        #pragma unroll 4
        for (int k = 0; k < HH; ++k) {
            float v = yp[k];
            #pragma unroll
            for (int j = 0; j < ON; ++j) accn[j] += v * nWs[k * ON + j];
            #pragma unroll
            for (int j = 0; j < OC; ++j) accg[j] += v * gWs[k * OC + j];
        }
        #pragma unroll
        for (int j = 0; j < ON; ++j) dout[OC + (size_t)n * ON + j] = accn[j];
    } else {
        #pragma unroll
        for (int j = 0; j < OC; ++j) accg[j] = -INFINITY;
    }
    #pragma unroll
    for (int j = 0; j < OC; ++j) {
        float m = accg[j];
        #pragma unroll
        for (int o = 1; o < 64; o <<= 1) m = fmaxf(m, __shfl_xor(m, o));
        if ((tid & 63) == 0) atomicMax(&genc[j], fenc(m));
    }
}

__global__ void k_gdec(const unsigned* __restrict__ genc, float* __restrict__ dout) {
    int t = threadIdx.x;
    if (t < OC) dout[t] = fdec(genc[t]);
}

// ---------- launch ----------
extern "C" void kernel_launch(void* const* d_in, const int* in_sizes, int n_in,
                              void* d_out, int out_size, void* d_ws, size_t ws_size,
                              hipStream_t stream) {
    const float* x     = (const float*)d_in[0];
    const float* nodeW = (const float*)d_in[1];
    const float* nodeB = (const float*)d_in[2];
    const float* W1    = (const float*)d_in[3];
    const float* b1    = (const float*)d_in[4];
    const float* mlg   = (const float*)d_in[5];
    const float* mlb   = (const float*)d_in[6];
    const float* W2    = (const float*)d_in[7];
    const float* b2    = (const float*)d_in[8];
    const float* tt    = (const float*)d_in[9];
    const float* lng   = (const float*)d_in[10];
    const float* lnb   = (const float*)d_in[11];
    const int*   ei    = (const int*)d_in[12];
    const float* gW    = (const float*)d_in[13];
    const float* gb    = (const float*)d_in[14];
    const float* nW    = (const float*)d_in[15];
    const float* nbp   = (const float*)d_in[16];
    float* out = (float*)d_out;

    char* ws = (char*)d_ws;
    size_t off = 0;
    auto alloc = [&](size_t bytes) -> void* {
        void* p = ws + off;
        off = (off + bytes + 255) & ~(size_t)255;
        return p;
    };
    int* counts    = (int*)alloc((size_t)NN * 4);
    int* cursor    = (int*)alloc((size_t)NN * 4);
    int* bsums     = (int*)alloc(1024);
    unsigned* genc = (unsigned*)alloc(64);
    size_t zero_end = off;
    int* rowst = (int*)alloc((size_t)NN * 4);
    int* ssrc  = (int*)alloc((size_t)NE * 4);
    float* h   = (float*)alloc((size_t)NN * HH * 4);
    float* y   = (float*)alloc((size_t)NN * HH * 4);
    float* ag  = (float*)alloc((size_t)NN * HH * 4);
    float* u   = (float*)alloc((size_t)NN * H2 * 4);

    const int* esrc = ei;
    const int* edst = ei + NE;

    hipMemsetAsync(d_ws, 0, zero_end, stream);

    k_hist<<<(NE + 255) / 256, 256, 0, stream>>>(edst, counts);
    k_scan1<<<SCAN_BLOCKS, 256, 0, stream>>>(counts, rowst, bsums);
    k_scan2<<<1, 256, 0, stream>>>(bsums);
    k_scan3<<<SCAN_BLOCKS, 256, 0, stream>>>(counts, rowst, bsums);
    k_scatter<<<(NE + 255) / 256, 256, 0, stream>>>(esrc, edst, rowst, cursor, ssrc);
    k_encoder<<<(NN + 3) / 4, 256, 0, stream>>>(x, nodeW, nodeB, h);

    for (int l = 0; l < NL; ++l) {
        const float* yin = h;
        if (l > 0) {
            k_lnrelu<<<(NN + 3) / 4, 256, 0, stream>>>(h, lng + l * HH, lnb + l * HH, y);
            yin = y;
        }
        k_agg<<<(NN + 3) / 4, 256, 0, stream>>>(yin, rowst, counts, ssrc, tt + l, ag);
        k_gemmA<<<(NN + 63) / 64, 256, 0, stream>>>(ag, W1 + (size_t)l * HH * H2, b1 + (size_t)l * H2, u);
        k_gemmB<<<(NN + 63) / 64, 256, 0, stream>>>(u, W2 + (size_t)l * H2 * HH, b2 + (size_t)l * HH,
                                                    mlg + (size_t)l * H2, mlb + (size_t)l * H2,
                                                    (l == 0) ? (const float*)nullptr : h, h);
    }
    k_lnrelu<<<(NN + 3) / 4, 256, 0, stream>>>(h, lng, lnb, y);
    k_out<<<(NN + 255) / 256, 256, 0, stream>>>(y, gW, gb, nW, nbp, out, genc);
    k_gdec<<<1, 64, 0, stream>>>(genc, out);
}

// Round 2
// 722.115 us; speedup vs baseline: 1.2866x; 1.2866x over previous
//
#include <hip/hip_runtime.h>

#define NN 50000
#define NE 800000
#define INC 32
#define HH 64
#define H2 128
#define OC 16
#define ON 17
#define NL 4
#define MEPS 1e-7f
#define LNE 1e-5f
#define SCAN_BLOCKS 196   /* ceil(50000/256) */

// ---------- ordered-uint encoding for float atomic max ----------
__device__ __forceinline__ unsigned fenc(float x) {
    unsigned u = __float_as_uint(x);
    return (u & 0x80000000u) ? ~u : (u | 0x80000000u);
}
__device__ __forceinline__ float fdec(unsigned u) {
    return (u & 0x80000000u) ? __uint_as_float(u & 0x7fffffffu)
                             : __uint_as_float(~u);
}

// ---------- CSR build ----------
__global__ __launch_bounds__(256) void k_hist(const int* __restrict__ dst, int* __restrict__ counts) {
    int e = blockIdx.x * 256 + threadIdx.x;
    if (e < NE) atomicAdd(&counts[dst[e]], 1);
}

__global__ __launch_bounds__(256) void k_scan1(const int* __restrict__ counts,
                                               int* __restrict__ incl, int* __restrict__ bsums) {
    __shared__ int s[256];
    int t = threadIdx.x;
    int i = blockIdx.x * 256 + t;
    int v = (i < NN) ? counts[i] : 0;
    s[t] = v;
    __syncthreads();
    for (int off = 1; off < 256; off <<= 1) {
        int x = (t >= off) ? s[t - off] : 0;
        __syncthreads();
        s[t] += x;
        __syncthreads();
    }
    if (i < NN) incl[i] = s[t];
    if (t == 255) bsums[blockIdx.x] = s[255];
}

__global__ __launch_bounds__(256) void k_scan2(int* __restrict__ bsums) {
    __shared__ int s[256];
    int t = threadIdx.x;
    int v = (t < SCAN_BLOCKS) ? bsums[t] : 0;
    s[t] = v;
    __syncthreads();
    for (int off = 1; off < 256; off <<= 1) {
        int x = (t >= off) ? s[t - off] : 0;
        __syncthreads();
        s[t] += x;
        __syncthreads();
    }
    if (t < SCAN_BLOCKS) bsums[t] = s[t] - v;  // exclusive
}

__global__ __launch_bounds__(256) void k_scan3(const int* __restrict__ counts,
                                               int* __restrict__ rowst, const int* __restrict__ bsums) {
    int i = blockIdx.x * 256 + threadIdx.x;
    if (i < NN) rowst[i] = rowst[i] - counts[i] + bsums[blockIdx.x];
}

__global__ __launch_bounds__(256) void k_scatter(const int* __restrict__ src, const int* __restrict__ dst,
                                                 const int* __restrict__ rowst, int* __restrict__ cursor,
                                                 int* __restrict__ ssrc) {
    int e = blockIdx.x * 256 + threadIdx.x;
    if (e < NE) {
        int d = dst[e];
        int pos = rowst[d] + atomicAdd(&cursor[d], 1);
        ssrc[pos] = src[e];
    }
}

// ---------- node encoder: h = x @ W + b  ([N,32]@[32,64]) ----------
__global__ __launch_bounds__(256) void k_encoder(const float* __restrict__ x, const float* __restrict__ W,
                                                 const float* __restrict__ b, float* __restrict__ h) {
    __shared__ float Ws[INC * HH];
    __shared__ float bs[HH];
    int tid = threadIdx.x;
    for (int i = tid; i < INC * HH; i += 256) Ws[i] = W[i];
    if (tid < HH) bs[tid] = b[tid];
    __syncthreads();
    int wid = tid >> 6, lane = tid & 63;
    int n = blockIdx.x * 4 + wid;
    if (n >= NN) return;
    float v = (lane < INC) ? x[(size_t)n * INC + lane] : 0.f;
    float acc = bs[lane];
    #pragma unroll
    for (int k = 0; k < INC; ++k)
        acc += __shfl(v, k) * Ws[k * HH + lane];
    h[(size_t)n * HH + lane] = acc;
}

// ---------- y = relu(LayerNorm(h))  (wave per node) ----------
__global__ __launch_bounds__(256) void k_lnrelu(const float* __restrict__ h, const float* __restrict__ g,
                                                const float* __restrict__ b, float* __restrict__ y) {
    int tid = threadIdx.x;
    int wid = tid >> 6, lane = tid & 63;
    int n = blockIdx.x * 4 + wid;
    if (n >= NN) return;
    float v = h[(size_t)n * HH + lane];
    float s = v;
    #pragma unroll
    for (int m = 1; m < 64; m <<= 1) s += __shfl_xor(s, m);
    float mu = s * (1.f / 64.f);
    float d = v - mu;
    float q = d * d;
    #pragma unroll
    for (int m = 1; m < 64; m <<= 1) q += __shfl_xor(q, m);
    float rs = rsqrtf(q * (1.f / 64.f) + LNE);
    float r = d * rs * g[lane] + b[lane];
    y[(size_t)n * HH + lane] = fmaxf(r, 0.f);
}

// ---------- per-dst softmax aggregation (no-max softmax: z >= 0 bounded, exp safe) ----------
// 8-wide edge chunks: 8 independent index loads -> 8 independent row gathers -> math.
__global__ __launch_bounds__(256) void k_agg(const float* __restrict__ y, const int* __restrict__ rowst,
                                             const int* __restrict__ counts, const int* __restrict__ ssrc,
                                             const float* __restrict__ tp, float* __restrict__ ag) {
    int tid = threadIdx.x;
    int wid = tid >> 6, lane = tid & 63;
    int n = blockIdx.x * 4 + wid;
    if (n >= NN) return;
    float tval = *tp;
    int start = rowst[n];
    int deg = counts[n];
    float Sa = 0.f, Sma = 0.f;
    int e = 0;
    for (; e + 8 <= deg; e += 8) {
        int s[8];
        #pragma unroll
        for (int i = 0; i < 8; ++i) s[i] = ssrc[start + e + i];
        float v[8];
        #pragma unroll
        for (int i = 0; i < 8; ++i) v[i] = y[(size_t)s[i] * HH + lane];
        #pragma unroll
        for (int i = 0; i < 8; ++i) {
            float m = fmaxf(v[i], 0.f) + MEPS;
            float a = __expf(tval * m);
            Sa += a; Sma += m * a;
        }
    }
    if (e < deg) {
        int rem = deg - e;   // 1..7
        int s[7];
        #pragma unroll
        for (int i = 0; i < 7; ++i) s[i] = (i < rem) ? ssrc[start + e + i] : 0;
        float v[7];
        #pragma unroll
        for (int i = 0; i < 7; ++i) v[i] = (i < rem) ? y[(size_t)s[i] * HH + lane] : 0.f;
        #pragma unroll
        for (int i = 0; i < 7; ++i) {
            if (i < rem) {
                float m = fmaxf(v[i], 0.f) + MEPS;
                float a = __expf(tval * m);
                Sa += a; Sma += m * a;
            }
        }
    }
    float agg = Sma / fmaxf(Sa, MEPS);  // deg==0 -> 0
    ag[(size_t)n * HH + lane] = agg + y[(size_t)n * HH + lane];
}

// ---------- GEMM A: U = ag @ W1 + b1  ([N,64]@[64,128]) ----------
__global__ __launch_bounds__(256) void k_gemmA(const float* __restrict__ A, const float* __restrict__ W,
                                               const float* __restrict__ bias, float* __restrict__ U) {
    __shared__ float As[64 * 68];     // pad 4 -> 2-way conflicts only (free)
    __shared__ float Bs[HH * H2];     // 8192
    __shared__ float bb[H2];
    int tid = threadIdx.x;
    int nb = blockIdx.x * 64;
    for (int i = tid; i < HH * H2 / 4; i += 256)
        ((float4*)Bs)[i] = ((const float4*)W)[i];
    if (tid < H2) bb[tid] = bias[tid];
    {
        int row = tid >> 2, cb = (tid & 3) * 16;
        int n = nb + row;
        float4* dp = (float4*)(As + row * 68 + cb);
        if (n < NN) {
            const float4* sp = (const float4*)(A + (size_t)n * HH + cb);
            #pragma unroll
            for (int i = 0; i < 4; ++i) dp[i] = sp[i];
        } else {
            float4 z = {0.f, 0.f, 0.f, 0.f};
            #pragma unroll
            for (int i = 0; i < 4; ++i) dp[i] = z;
        }
    }
    __syncthreads();
    int tx = tid & 15, ty = tid >> 4;
    int r0 = ty * 4, j0 = tx * 8;
    float acc[4][8] = {};
    #pragma unroll 8
    for (int k = 0; k < HH; ++k) {
        float4 b0 = *(const float4*)(Bs + k * H2 + j0);
        float4 b1 = *(const float4*)(Bs + k * H2 + j0 + 4);
        #pragma unroll
        for (int r = 0; r < 4; ++r) {
            float a = As[(r0 + r) * 68 + k];
            acc[r][0] += a * b0.x; acc[r][1] += a * b0.y;
            acc[r][2] += a * b0.z; acc[r][3] += a * b0.w;
            acc[r][4] += a * b1.x; acc[r][5] += a * b1.y;
            acc[r][6] += a * b1.z; acc[r][7] += a * b1.w;
        }
    }
    #pragma unroll
    for (int r = 0; r < 4; ++r) {
        int n = nb + r0 + r;
        if (n < NN) {
            float4 o0, o1;
            o0.x = acc[r][0] + bb[j0];     o0.y = acc[r][1] + bb[j0 + 1];
            o0.z = acc[r][2] + bb[j0 + 2]; o0.w = acc[r][3] + bb[j0 + 3];
            o1.x = acc[r][4] + bb[j0 + 4]; o1.y = acc[r][5] + bb[j0 + 5];
            o1.z = acc[r][6] + bb[j0 + 6]; o1.w = acc[r][7] + bb[j0 + 7];
            *(float4*)(U + (size_t)n * H2 + j0) = o0;
            *(float4*)(U + (size_t)n * H2 + j0 + 4) = o1;
        }
    }
}

// ---------- GEMM B with fused LN(128)+ReLU on input tile, +bias, +optional residual ----------
__global__ __launch_bounds__(256) void k_gemmB(const float* __restrict__ U, const float* __restrict__ W,
                                               const float* __restrict__ bias,
                                               const float* __restrict__ lng, const float* __restrict__ lnb,
                                               const float* __restrict__ hres, float* __restrict__ hout) {
    __shared__ float As[64 * 132];    // pad 4
    __shared__ float Bs[H2 * HH];     // 8192
    __shared__ float bb[HH];
    __shared__ float lg[H2], lb[H2];
    __shared__ float ps[64 * 4], psq[64 * 4];
    __shared__ float mus[64], rss[64];
    int tid = threadIdx.x;
    int nb = blockIdx.x * 64;
    for (int i = tid; i < H2 * HH / 4; i += 256)
        ((float4*)Bs)[i] = ((const float4*)W)[i];
    if (tid < HH) bb[tid] = bias[tid];
    if (tid < H2) { lg[tid] = lng[tid]; lb[tid] = lnb[tid]; }
    {
        int row = tid >> 2, cb = (tid & 3) * 32;
        int n = nb + row;
        float4* dp = (float4*)(As + row * 132 + cb);
        if (n < NN) {
            const float4* sp = (const float4*)(U + (size_t)n * H2 + cb);
            #pragma unroll
            for (int i = 0; i < 8; ++i) dp[i] = sp[i];
        } else {
            float4 z = {0.f, 0.f, 0.f, 0.f};
            #pragma unroll
            for (int i = 0; i < 8; ++i) dp[i] = z;
        }
    }
    __syncthreads();
    // LN stats: thread (row, q) handles cols {q, q+4, q+8, ...} (bank-spread)
    {
        int row = tid >> 2, q = tid & 3;
        const float* rp = As + row * 132;
        float s = 0.f, sq = 0.f;
        #pragma unroll
        for (int i = 0; i < 32; ++i) { float v = rp[i * 4 + q]; s += v; sq += v * v; }
        ps[row * 4 + q] = s; psq[row * 4 + q] = sq;
    }
    __syncthreads();
    if (tid < 64) {
        float s = ps[tid * 4] + ps[tid * 4 + 1] + ps[tid * 4 + 2] + ps[tid * 4 + 3];
        float sq = psq[tid * 4] + psq[tid * 4 + 1] + psq[tid * 4 + 2] + psq[tid * 4 + 3];
        float mu = s * (1.f / 128.f);
        float var = sq * (1.f / 128.f) - mu * mu;
        mus[tid] = mu;
        rss[tid] = rsqrtf(fmaxf(var, 0.f) + LNE);
    }
    __syncthreads();
    {
        int row = tid >> 2, q = tid & 3;
        float mu = mus[row], rs = rss[row];
        float* rp = As + row * 132;
        #pragma unroll
        for (int i = 0; i < 32; ++i) {
            int c = i * 4 + q;
            float v = (rp[c] - mu) * rs * lg[c] + lb[c];
            rp[c] = fmaxf(v, 0.f);
        }
    }
    __syncthreads();
    int tx = tid & 15, ty = tid >> 4;
    int r0 = ty * 4, o0 = tx * 4;
    float acc[4][4] = {};
    #pragma unroll 8
    for (int k = 0; k < H2; ++k) {
        float4 b4 = *(const float4*)(Bs + k * HH + o0);
        #pragma unroll
        for (int r = 0; r < 4; ++r) {
            float a = As[(r0 + r) * 132 + k];
            acc[r][0] += a * b4.x; acc[r][1] += a * b4.y;
            acc[r][2] += a * b4.z; acc[r][3] += a * b4.w;
        }
    }
    #pragma unroll
    for (int r = 0; r < 4; ++r) {
        int n = nb + r0 + r;
        if (n < NN) {
            float4 o;
            o.x = acc[r][0] + bb[o0];     o.y = acc[r][1] + bb[o0 + 1];
            o.z = acc[r][2] + bb[o0 + 2]; o.w = acc[r][3] + bb[o0 + 3];
            if (hres) {
                float4 hr = *(const float4*)(hres + (size_t)n * HH + o0);
                o.x += hr.x; o.y += hr.y; o.z += hr.z; o.w += hr.w;
            }
            *(float4*)(hout + (size_t)n * HH + o0) = o;
        }
    }
}

// ---------- output heads: wave per node, lane = channel ----------
__global__ __launch_bounds__(1024) void k_out(const float* __restrict__ y,
                                              const float* __restrict__ gW, const float* __restrict__ gb,
                                              const float* __restrict__ nW, const float* __restrict__ nbp,
                                              float* __restrict__ dout, unsigned* __restrict__ genc) {
    __shared__ float red[16][OC + 1];
    int tid = threadIdx.x;
    int wid = tid >> 6, lane = tid & 63;
    int n = blockIdx.x * 16 + wid;
    // per-lane weight rows: lane k holds nW[k,*], gW[k,*]
    float wn[ON];
    #pragma unroll
    for (int j = 0; j < ON; ++j) wn[j] = nW[lane * ON + j];
    float wg[OC];
    #pragma unroll
    for (int j = 0; j < OC; ++j) wg[j] = gW[lane * OC + j];
    float bn = (lane < ON) ? nbp[lane] : 0.f;
    float bg = (lane < OC) ? gb[lane] : 0.f;
    float v = (n < NN) ? y[(size_t)n * HH + lane] : 0.f;
    float resn = 0.f, resg = -INFINITY;
    #pragma unroll
    for (int j = 0; j < ON; ++j) {
        float p = v * wn[j];
        #pragma unroll
        for (int o = 1; o < 64; o <<= 1) p += __shfl_xor(p, o);
        if (lane == j) resn = p + bn;
    }
    #pragma unroll
    for (int j = 0; j < OC; ++j) {
        float p = v * wg[j];
        #pragma unroll
        for (int o = 1; o < 64; o <<= 1) p += __shfl_xor(p, o);
        if (lane == j) resg = p + bg;
    }
    if (n < NN && lane < ON) dout[OC + (size_t)n * ON + lane] = resn;
    if (n >= NN) resg = -INFINITY;
    if (lane < OC) red[wid][lane] = resg;
    __syncthreads();
    if (tid < OC) {
        float m = -INFINITY;
        #pragma unroll
        for (int w = 0; w < 16; ++w) m = fmaxf(m, red[w][tid]);
        atomicMax(&genc[tid], fenc(m));
    }
}

__global__ void k_gdec(const unsigned* __restrict__ genc, float* __restrict__ dout) {
    int t = threadIdx.x;
    if (t < OC) dout[t] = fdec(genc[t]);
}

// ---------- launch ----------
extern "C" void kernel_launch(void* const* d_in, const int* in_sizes, int n_in,
                              void* d_out, int out_size, void* d_ws, size_t ws_size,
                              hipStream_t stream) {
    const float* x     = (const float*)d_in[0];
    const float* nodeW = (const float*)d_in[1];
    const float* nodeB = (const float*)d_in[2];
    const float* W1    = (const float*)d_in[3];
    const float* b1    = (const float*)d_in[4];
    const float* mlg   = (const float*)d_in[5];
    const float* mlb   = (const float*)d_in[6];
    const float* W2    = (const float*)d_in[7];
    const float* b2    = (const float*)d_in[8];
    const float* tt    = (const float*)d_in[9];
    const float* lng   = (const float*)d_in[10];
    const float* lnb   = (const float*)d_in[11];
    const int*   ei    = (const int*)d_in[12];
    const float* gW    = (const float*)d_in[13];
    const float* gb    = (const float*)d_in[14];
    const float* nW    = (const float*)d_in[15];
    const float* nbp   = (const float*)d_in[16];
    float* out = (float*)d_out;

    char* ws = (char*)d_ws;
    size_t off = 0;
    auto alloc = [&](size_t bytes) -> void* {
        void* p = ws + off;
        off = (off + bytes + 255) & ~(size_t)255;
        return p;
    };
    int* counts    = (int*)alloc((size_t)NN * 4);
    int* cursor    = (int*)alloc((size_t)NN * 4);
    int* bsums     = (int*)alloc(1024);
    unsigned* genc = (unsigned*)alloc(64);
    size_t zero_end = off;
    int* rowst = (int*)alloc((size_t)NN * 4);
    int* ssrc  = (int*)alloc((size_t)NE * 4);
    float* h   = (float*)alloc((size_t)NN * HH * 4);
    float* y   = (float*)alloc((size_t)NN * HH * 4);
    float* ag  = (float*)alloc((size_t)NN * HH * 4);
    float* u   = (float*)alloc((size_t)NN * H2 * 4);

    const int* esrc = ei;
    const int* edst = ei + NE;

    hipMemsetAsync(d_ws, 0, zero_end, stream);

    k_hist<<<(NE + 255) / 256, 256, 0, stream>>>(edst, counts);
    k_scan1<<<SCAN_BLOCKS, 256, 0, stream>>>(counts, rowst, bsums);
    k_scan2<<<1, 256, 0, stream>>>(bsums);
    k_scan3<<<SCAN_BLOCKS, 256, 0, stream>>>(counts, rowst, bsums);
    k_scatter<<<(NE + 255) / 256, 256, 0, stream>>>(esrc, edst, rowst, cursor, ssrc);
    k_encoder<<<(NN + 3) / 4, 256, 0, stream>>>(x, nodeW, nodeB, h);

    for (int l = 0; l < NL; ++l) {
        const float* yin = h;
        if (l > 0) {
            k_lnrelu<<<(NN + 3) / 4, 256, 0, stream>>>(h, lng + l * HH, lnb + l * HH, y);
            yin = y;
        }
        k_agg<<<(NN + 3) / 4, 256, 0, stream>>>(yin, rowst, counts, ssrc, tt + l, ag);
        k_gemmA<<<(NN + 63) / 64, 256, 0, stream>>>(ag, W1 + (size_t)l * HH * H2, b1 + (size_t)l * H2, u);
        k_gemmB<<<(NN + 63) / 64, 256, 0, stream>>>(u, W2 + (size_t)l * H2 * HH, b2 + (size_t)l * HH,
                                                    mlg + (size_t)l * H2, mlb + (size_t)l * H2,
                                                    (l == 0) ? (const float*)nullptr : h, h);
    }
    k_lnrelu<<<(NN + 3) / 4, 256, 0, stream>>>(h, lng, lnb, y);
    k_out<<<(NN + 15) / 16, 1024, 0, stream>>>(y, gW, gb, nW, nbp, out, genc);
    k_gdec<<<1, 64, 0, stream>>>(genc, out);
}

// Round 3
// 609.720 us; speedup vs baseline: 1.5238x; 1.1843x over previous
//
#include <hip/hip_runtime.h>

#define NN 50000
#define NE 800000
#define INC 32
#define HH 64
#define H2 128
#define OC 16
#define ON 17
#define WOUT 33
#define NL 4
#define MEPS 1e-7f
#define LNE 1e-5f
#define SCAN_BLOCKS 196   /* ceil(50000/256) */

// ---------- ordered-uint encoding for float atomic max ----------
__device__ __forceinline__ unsigned fenc(float x) {
    unsigned u = __float_as_uint(x);
    return (u & 0x80000000u) ? ~u : (u | 0x80000000u);
}
__device__ __forceinline__ float fdec(unsigned u) {
    return (u & 0x80000000u) ? __uint_as_float(u & 0x7fffffffu)
                             : __uint_as_float(~u);
}
// ---------- bf16 helpers (RNE) ----------
__device__ __forceinline__ unsigned short f2b(float x) {
    unsigned b = __float_as_uint(x);
    b += 0x7FFFu + ((b >> 16) & 1u);
    return (unsigned short)(b >> 16);
}
__device__ __forceinline__ float b2f(unsigned short u) {
    return __uint_as_float(((unsigned)u) << 16);
}

// ---------- CSR build ----------
__global__ __launch_bounds__(256) void k_hist(const int* __restrict__ dst, int* __restrict__ counts) {
    int e = blockIdx.x * 256 + threadIdx.x;
    if (e < NE) atomicAdd(&counts[dst[e]], 1);
}

__global__ __launch_bounds__(256) void k_scan1(const int* __restrict__ counts,
                                               int* __restrict__ incl, int* __restrict__ bsums) {
    __shared__ int s[256];
    int t = threadIdx.x;
    int i = blockIdx.x * 256 + t;
    int v = (i < NN) ? counts[i] : 0;
    s[t] = v;
    __syncthreads();
    for (int off = 1; off < 256; off <<= 1) {
        int x = (t >= off) ? s[t - off] : 0;
        __syncthreads();
        s[t] += x;
        __syncthreads();
    }
    if (i < NN) incl[i] = s[t];
    if (t == 255) bsums[blockIdx.x] = s[255];
}

__global__ __launch_bounds__(256) void k_scan2(int* __restrict__ bsums) {
    __shared__ int s[256];
    int t = threadIdx.x;
    int v = (t < SCAN_BLOCKS) ? bsums[t] : 0;
    s[t] = v;
    __syncthreads();
    for (int off = 1; off < 256; off <<= 1) {
        int x = (t >= off) ? s[t - off] : 0;
        __syncthreads();
        s[t] += x;
        __syncthreads();
    }
    if (t < SCAN_BLOCKS) bsums[t] = s[t] - v;  // exclusive
}

__global__ __launch_bounds__(256) void k_scan3(const int* __restrict__ counts,
                                               int* __restrict__ rowst, const int* __restrict__ bsums) {
    int i = blockIdx.x * 256 + threadIdx.x;
    if (i < NN) rowst[i] = rowst[i] - counts[i] + bsums[blockIdx.x];
}

__global__ __launch_bounds__(256) void k_scatter(const int* __restrict__ src, const int* __restrict__ dst,
                                                 const int* __restrict__ rowst, int* __restrict__ cursor,
                                                 int* __restrict__ ssrc) {
    int e = blockIdx.x * 256 + threadIdx.x;
    if (e < NE) {
        int d = dst[e];
        int pos = rowst[d] + atomicAdd(&cursor[d], 1);
        ssrc[pos] = src[e];
    }
}

// ---------- node encoder: h = x @ W + b  ([N,32]@[32,64]), also bf16 shadow ----------
__global__ __launch_bounds__(256) void k_encoder(const float* __restrict__ x, const float* __restrict__ W,
                                                 const float* __restrict__ b, float* __restrict__ h,
                                                 unsigned short* __restrict__ hbf) {
    __shared__ float Ws[INC * HH];
    __shared__ float bs[HH];
    int tid = threadIdx.x;
    for (int i = tid; i < INC * HH; i += 256) Ws[i] = W[i];
    if (tid < HH) bs[tid] = b[tid];
    __syncthreads();
    int wid = tid >> 6, lane = tid & 63;
    int n = blockIdx.x * 4 + wid;
    if (n >= NN) return;
    float v = (lane < INC) ? x[(size_t)n * INC + lane] : 0.f;
    float acc = bs[lane];
    #pragma unroll
    for (int k = 0; k < INC; ++k)
        acc += __shfl(v, k) * Ws[k * HH + lane];
    h[(size_t)n * HH + lane] = acc;
    hbf[(size_t)n * HH + lane] = f2b(acc);
}

// ---------- y = relu(LayerNorm(h)), fp32 + bf16 shadow ----------
__global__ __launch_bounds__(256) void k_lnrelu(const float* __restrict__ h, const float* __restrict__ g,
                                                const float* __restrict__ b, float* __restrict__ y,
                                                unsigned short* __restrict__ ybf) {
    int tid = threadIdx.x;
    int wid = tid >> 6, lane = tid & 63;
    int n = blockIdx.x * 4 + wid;
    if (n >= NN) return;
    float v = h[(size_t)n * HH + lane];
    float s = v;
    #pragma unroll
    for (int m = 1; m < 64; m <<= 1) s += __shfl_xor(s, m);
    float mu = s * (1.f / 64.f);
    float d = v - mu;
    float q = d * d;
    #pragma unroll
    for (int m = 1; m < 64; m <<= 1) q += __shfl_xor(q, m);
    float rs = rsqrtf(q * (1.f / 64.f) + LNE);
    float r = fmaxf(d * rs * g[lane] + b[lane], 0.f);
    y[(size_t)n * HH + lane] = r;
    if (ybf) ybf[(size_t)n * HH + lane] = f2b(r);
}

// ---------- per-dst softmax aggregation ----------
// One index load per node; double-buffered 8-row chunks with unconditional
// (clamped) gathers so the compiler can emit static vmcnt; masked math.
// Gathers read the bf16 shadow (128 B rows); root add uses fp32 y.
__global__ __launch_bounds__(256) void k_agg(const float* __restrict__ y,
                                             const unsigned short* __restrict__ ybf,
                                             const int* __restrict__ rowst,
                                             const int* __restrict__ counts, const int* __restrict__ ssrc,
                                             const float* __restrict__ tp, float* __restrict__ ag) {
    int tid = threadIdx.x;
    int wid = tid >> 6, lane = tid & 63;
    int n = blockIdx.x * 4 + wid;
    if (n >= NN) return;
    float tval = *tp;
    int start = rowst[n];
    int deg = counts[n];
    float Sa = 0.f, Sma = 0.f;
    if (deg > 0 && deg <= 64) {
        int myidx = (lane < deg) ? ssrc[start + lane] : 0;
        int T = (deg + 7) >> 3;          // chunks
        int c0 = deg - ((T - 1) << 3);   // 1..8, first chunk size
        float va[8], vb[8];
        #pragma unroll
        for (int i = 0; i < 8; ++i) {
            int ii = (i < c0) ? i : (c0 - 1);      // clamp -> repeats a row (L1 hit)
            int s = __shfl(myidx, ii);
            va[i] = b2f(ybf[(size_t)s * HH + lane]);
        }
        int base = c0;
        int cs = c0;
        for (int t = 0; t < T - 1; ++t) {
            #pragma unroll
            for (int i = 0; i < 8; ++i) {
                int s = __shfl(myidx, base + i);
                vb[i] = b2f(ybf[(size_t)s * HH + lane]);
            }
            base += 8;
            #pragma unroll
            for (int i = 0; i < 8; ++i) {
                float m = fmaxf(va[i], 0.f) + MEPS;
                float a = (i < cs) ? __expf(tval * m) : 0.f;
                Sa += a; Sma += m * a;
            }
            cs = 8;
            #pragma unroll
            for (int i = 0; i < 8; ++i) va[i] = vb[i];
        }
        #pragma unroll
        for (int i = 0; i < 8; ++i) {
            float m = fmaxf(va[i], 0.f) + MEPS;
            float a = (i < cs) ? __expf(tval * m) : 0.f;
            Sa += a; Sma += m * a;
        }
    } else if (deg > 64) {
        for (int e = 0; e < deg; ++e) {
            int s = ssrc[start + e];
            float v = b2f(ybf[(size_t)s * HH + lane]);
            float m = fmaxf(v, 0.f) + MEPS;
            float a = __expf(tval * m);
            Sa += a; Sma += m * a;
        }
    }
    float agg = Sma / fmaxf(Sa, MEPS);  // deg==0 -> 0
    ag[(size_t)n * HH + lane] = agg + y[(size_t)n * HH + lane];
}

// ---------- GEMM A: U = ag @ W1 + b1  ([N,64]@[64,128]) ----------
__global__ __launch_bounds__(256) void k_gemmA(const float* __restrict__ A, const float* __restrict__ W,
                                               const float* __restrict__ bias, float* __restrict__ U) {
    __shared__ float As[64 * 68];     // pad 4 -> 2-way conflicts only (free)
    __shared__ float Bs[HH * H2];     // 8192
    __shared__ float bb[H2];
    int tid = threadIdx.x;
    int nb = blockIdx.x * 64;
    for (int i = tid; i < HH * H2 / 4; i += 256)
        ((float4*)Bs)[i] = ((const float4*)W)[i];
    if (tid < H2) bb[tid] = bias[tid];
    {
        int row = tid >> 2, cb = (tid & 3) * 16;
        int n = nb + row;
        float4* dp = (float4*)(As + row * 68 + cb);
        if (n < NN) {
            const float4* sp = (const float4*)(A + (size_t)n * HH + cb);
            #pragma unroll
            for (int i = 0; i < 4; ++i) dp[i] = sp[i];
        } else {
            float4 z = {0.f, 0.f, 0.f, 0.f};
            #pragma unroll
            for (int i = 0; i < 4; ++i) dp[i] = z;
        }
    }
    __syncthreads();
    int tx = tid & 15, ty = tid >> 4;
    int r0 = ty * 4, j0 = tx * 8;
    float acc[4][8] = {};
    #pragma unroll 8
    for (int k = 0; k < HH; ++k) {
        float4 b0 = *(const float4*)(Bs + k * H2 + j0);
        float4 b1 = *(const float4*)(Bs + k * H2 + j0 + 4);
        #pragma unroll
        for (int r = 0; r < 4; ++r) {
            float a = As[(r0 + r) * 68 + k];
            acc[r][0] += a * b0.x; acc[r][1] += a * b0.y;
            acc[r][2] += a * b0.z; acc[r][3] += a * b0.w;
            acc[r][4] += a * b1.x; acc[r][5] += a * b1.y;
            acc[r][6] += a * b1.z; acc[r][7] += a * b1.w;
        }
    }
    #pragma unroll
    for (int r = 0; r < 4; ++r) {
        int n = nb + r0 + r;
        if (n < NN) {
            float4 o0, o1;
            o0.x = acc[r][0] + bb[j0];     o0.y = acc[r][1] + bb[j0 + 1];
            o0.z = acc[r][2] + bb[j0 + 2]; o0.w = acc[r][3] + bb[j0 + 3];
            o1.x = acc[r][4] + bb[j0 + 4]; o1.y = acc[r][5] + bb[j0 + 5];
            o1.z = acc[r][6] + bb[j0 + 6]; o1.w = acc[r][7] + bb[j0 + 7];
            *(float4*)(U + (size_t)n * H2 + j0) = o0;
            *(float4*)(U + (size_t)n * H2 + j0 + 4) = o1;
        }
    }
}

// ---------- GEMM B with fused LN(128)+ReLU on input tile, +bias, +optional residual ----------
__global__ __launch_bounds__(256) void k_gemmB(const float* __restrict__ U, const float* __restrict__ W,
                                               const float* __restrict__ bias,
                                               const float* __restrict__ lng, const float* __restrict__ lnb,
                                               const float* __restrict__ hres, float* __restrict__ hout) {
    __shared__ float As[64 * 132];    // pad 4
    __shared__ float Bs[H2 * HH];     // 8192
    __shared__ float bb[HH];
    __shared__ float lg[H2], lb[H2];
    __shared__ float ps[64 * 4], psq[64 * 4];
    __shared__ float mus[64], rss[64];
    int tid = threadIdx.x;
    int nb = blockIdx.x * 64;
    for (int i = tid; i < H2 * HH / 4; i += 256)
        ((float4*)Bs)[i] = ((const float4*)W)[i];
    if (tid < HH) bb[tid] = bias[tid];
    if (tid < H2) { lg[tid] = lng[tid]; lb[tid] = lnb[tid]; }
    {
        int row = tid >> 2, cb = (tid & 3) * 32;
        int n = nb + row;
        float4* dp = (float4*)(As + row * 132 + cb);
        if (n < NN) {
            const float4* sp = (const float4*)(U + (size_t)n * H2 + cb);
            #pragma unroll
            for (int i = 0; i < 8; ++i) dp[i] = sp[i];
        } else {
            float4 z = {0.f, 0.f, 0.f, 0.f};
            #pragma unroll
            for (int i = 0; i < 8; ++i) dp[i] = z;
        }
    }
    __syncthreads();
    {
        int row = tid >> 2, q = tid & 3;
        const float* rp = As + row * 132;
        float s = 0.f, sq = 0.f;
        #pragma unroll
        for (int i = 0; i < 32; ++i) { float v = rp[i * 4 + q]; s += v; sq += v * v; }
        ps[row * 4 + q] = s; psq[row * 4 + q] = sq;
    }
    __syncthreads();
    if (tid < 64) {
        float s = ps[tid * 4] + ps[tid * 4 + 1] + ps[tid * 4 + 2] + ps[tid * 4 + 3];
        float sq = psq[tid * 4] + psq[tid * 4 + 1] + psq[tid * 4 + 2] + psq[tid * 4 + 3];
        float mu = s * (1.f / 128.f);
        float var = sq * (1.f / 128.f) - mu * mu;
        mus[tid] = mu;
        rss[tid] = rsqrtf(fmaxf(var, 0.f) + LNE);
    }
    __syncthreads();
    {
        int row = tid >> 2, q = tid & 3;
        float mu = mus[row], rs = rss[row];
        float* rp = As + row * 132;
        #pragma unroll
        for (int i = 0; i < 32; ++i) {
            int c = i * 4 + q;
            float v = (rp[c] - mu) * rs * lg[c] + lb[c];
            rp[c] = fmaxf(v, 0.f);
        }
    }
    __syncthreads();
    int tx = tid & 15, ty = tid >> 4;
    int r0 = ty * 4, o0 = tx * 4;
    float acc[4][4] = {};
    #pragma unroll 8
    for (int k = 0; k < H2; ++k) {
        float4 b4 = *(const float4*)(Bs + k * HH + o0);
        #pragma unroll
        for (int r = 0; r < 4; ++r) {
            float a = As[(r0 + r) * 132 + k];
            acc[r][0] += a * b4.x; acc[r][1] += a * b4.y;
            acc[r][2] += a * b4.z; acc[r][3] += a * b4.w;
        }
    }
    #pragma unroll
    for (int r = 0; r < 4; ++r) {
        int n = nb + r0 + r;
        if (n < NN) {
            float4 o;
            o.x = acc[r][0] + bb[o0];     o.y = acc[r][1] + bb[o0 + 1];
            o.z = acc[r][2] + bb[o0 + 2]; o.w = acc[r][3] + bb[o0 + 3];
            if (hres) {
                float4 hr = *(const float4*)(hres + (size_t)n * HH + o0);
                o.x += hr.x; o.y += hr.y; o.z += hr.z; o.w += hr.w;
            }
            *(float4*)(hout + (size_t)n * HH + o0) = o;
        }
    }
}

// ---------- output heads: wave per node, LDS weights, broadcast-dot ----------
__global__ __launch_bounds__(1024) void k_out(const float* __restrict__ y,
                                              const float* __restrict__ gW, const float* __restrict__ gb,
                                              const float* __restrict__ nW, const float* __restrict__ nbp,
                                              float* __restrict__ dout, unsigned* __restrict__ genc) {
    __shared__ float Ws[HH * WOUT + 64];   // Ws[k][j]: j<17 n-head, j in [17,33) g-head
    __shared__ float bs[WOUT];
    __shared__ float red[16][OC];
    int tid = threadIdx.x;
    for (int i = tid; i < HH * ON; i += 1024) { int k = i / ON, j = i % ON; Ws[k * WOUT + j] = nW[i]; }
    for (int i = tid; i < HH * OC; i += 1024) { int k = i / OC, j = i % OC; Ws[k * WOUT + ON + j] = gW[i]; }
    if (tid < ON) bs[tid] = nbp[tid];
    else if (tid < WOUT) bs[tid] = gb[tid - ON];
    __syncthreads();
    int wid = tid >> 6, lane = tid & 63;
    int n = blockIdx.x * 16 + wid;
    float v = (n < NN) ? y[(size_t)n * HH + lane] : 0.f;
    float acc = (lane < WOUT) ? bs[lane] : 0.f;
    #pragma unroll
    for (int k = 0; k < HH; ++k) {
        float b = __shfl(v, k);
        acc += b * Ws[k * WOUT + lane];   // lanes >= 33 compute garbage (unused)
    }
    if (n < NN && lane < ON) dout[OC + (size_t)n * ON + lane] = acc;
    if (lane >= ON && lane < WOUT)
        red[wid][lane - ON] = (n < NN) ? acc : -INFINITY;
    __syncthreads();
    if (tid < OC) {
        float m = -INFINITY;
        #pragma unroll
        for (int w = 0; w < 16; ++w) m = fmaxf(m, red[w][tid]);
        atomicMax(&genc[tid], fenc(m));
    }
}

__global__ void k_gdec(const unsigned* __restrict__ genc, float* __restrict__ dout) {
    int t = threadIdx.x;
    if (t < OC) dout[t] = fdec(genc[t]);
}

// ---------- launch ----------
extern "C" void kernel_launch(void* const* d_in, const int* in_sizes, int n_in,
                              void* d_out, int out_size, void* d_ws, size_t ws_size,
                              hipStream_t stream) {
    const float* x     = (const float*)d_in[0];
    const float* nodeW = (const float*)d_in[1];
    const float* nodeB = (const float*)d_in[2];
    const float* W1    = (const float*)d_in[3];
    const float* b1    = (const float*)d_in[4];
    const float* mlg   = (const float*)d_in[5];
    const float* mlb   = (const float*)d_in[6];
    const float* W2    = (const float*)d_in[7];
    const float* b2    = (const float*)d_in[8];
    const float* tt    = (const float*)d_in[9];
    const float* lng   = (const float*)d_in[10];
    const float* lnb   = (const float*)d_in[11];
    const int*   ei    = (const int*)d_in[12];
    const float* gW    = (const float*)d_in[13];
    const float* gb    = (const float*)d_in[14];
    const float* nW    = (const float*)d_in[15];
    const float* nbp   = (const float*)d_in[16];
    float* out = (float*)d_out;

    char* ws = (char*)d_ws;
    size_t off = 0;
    auto alloc = [&](size_t bytes) -> void* {
        void* p = ws + off;
        off = (off + bytes + 255) & ~(size_t)255;
        return p;
    };
    int* counts    = (int*)alloc((size_t)NN * 4);
    int* cursor    = (int*)alloc((size_t)NN * 4);
    int* bsums     = (int*)alloc(1024);
    unsigned* genc = (unsigned*)alloc(64);
    size_t zero_end = off;
    int* rowst = (int*)alloc((size_t)NN * 4);
    int* ssrc  = (int*)alloc((size_t)NE * 4);
    float* h   = (float*)alloc((size_t)NN * HH * 4);
    float* y   = (float*)alloc((size_t)NN * HH * 4);
    float* ag  = (float*)alloc((size_t)NN * HH * 4);
    float* u   = (float*)alloc((size_t)NN * H2 * 4);
    unsigned short* ybf = (unsigned short*)alloc((size_t)NN * HH * 2);

    const int* esrc = ei;
    const int* edst = ei + NE;

    hipMemsetAsync(d_ws, 0, zero_end, stream);

    k_hist<<<(NE + 255) / 256, 256, 0, stream>>>(edst, counts);
    k_scan1<<<SCAN_BLOCKS, 256, 0, stream>>>(counts, rowst, bsums);
    k_scan2<<<1, 256, 0, stream>>>(bsums);
    k_scan3<<<SCAN_BLOCKS, 256, 0, stream>>>(counts, rowst, bsums);
    k_scatter<<<(NE + 255) / 256, 256, 0, stream>>>(esrc, edst, rowst, cursor, ssrc);
    k_encoder<<<(NN + 3) / 4, 256, 0, stream>>>(x, nodeW, nodeB, h, ybf);

    for (int l = 0; l < NL; ++l) {
        const float* yin = h;
        if (l > 0) {
            k_lnrelu<<<(NN + 3) / 4, 256, 0, stream>>>(h, lng + l * HH, lnb + l * HH, y, ybf);
            yin = y;
        }
        k_agg<<<(NN + 3) / 4, 256, 0, stream>>>(yin, ybf, rowst, counts, ssrc, tt + l, ag);
        k_gemmA<<<(NN + 63) / 64, 256, 0, stream>>>(ag, W1 + (size_t)l * HH * H2, b1 + (size_t)l * H2, u);
        k_gemmB<<<(NN + 63) / 64, 256, 0, stream>>>(u, W2 + (size_t)l * H2 * HH, b2 + (size_t)l * HH,
                                                    mlg + (size_t)l * H2, mlb + (size_t)l * H2,
                                                    (l == 0) ? (const float*)nullptr : h, h);
    }
    k_lnrelu<<<(NN + 3) / 4, 256, 0, stream>>>(h, lng, lnb, y, (unsigned short*)nullptr);
    k_out<<<(NN + 15) / 16, 1024, 0, stream>>>(y, gW, gb, nW, nbp, out, genc);
    k_gdec<<<1, 64, 0, stream>>>(genc, out);
}

// Round 4
// 539.088 us; speedup vs baseline: 1.7235x; 1.1310x over previous
//
#include <hip/hip_runtime.h>

#define NN 50000
#define NE 800000
#define INC 32
#define HH 64
#define H2 128
#define OC 16
#define ON 17
#define NL 4
#define MEPS 1e-7f
#define LNE 1e-5f
#define SCAN_BLOCKS 196   /* ceil(50000/256) */

// ---------- ordered-uint encoding for float atomic max ----------
__device__ __forceinline__ unsigned fenc(float x) {
    unsigned u = __float_as_uint(x);
    return (u & 0x80000000u) ? ~u : (u | 0x80000000u);
}
__device__ __forceinline__ float fdec(unsigned u) {
    return (u & 0x80000000u) ? __uint_as_float(u & 0x7fffffffu)
                             : __uint_as_float(~u);
}
// ---------- bf16 helpers (RNE) ----------
__device__ __forceinline__ unsigned short f2b(float x) {
    unsigned b = __float_as_uint(x);
    b += 0x7FFFu + ((b >> 16) & 1u);
    return (unsigned short)(b >> 16);
}
__device__ __forceinline__ float b2f(unsigned short u) {
    return __uint_as_float(((unsigned)u) << 16);
}

// ---------- CSR build ----------
// hist + rank in one pass: atomicAdd's return value is this edge's rank among
// same-dst edges. Scatter pass then needs no atomics at all.
__global__ __launch_bounds__(256) void k_hist2(const int* __restrict__ dst, int* __restrict__ counts,
                                               int* __restrict__ rank) {
    int e = blockIdx.x * 256 + threadIdx.x;
    if (e < NE) rank[e] = atomicAdd(&counts[dst[e]], 1);
}

__global__ __launch_bounds__(256) void k_scan1(const int* __restrict__ counts,
                                               int* __restrict__ incl, int* __restrict__ bsums) {
    __shared__ int s[256];
    int t = threadIdx.x;
    int i = blockIdx.x * 256 + t;
    int v = (i < NN) ? counts[i] : 0;
    s[t] = v;
    __syncthreads();
    for (int off = 1; off < 256; off <<= 1) {
        int x = (t >= off) ? s[t - off] : 0;
        __syncthreads();
        s[t] += x;
        __syncthreads();
    }
    if (i < NN) incl[i] = s[t];
    if (t == 255) bsums[blockIdx.x] = s[255];
}

__global__ __launch_bounds__(256) void k_scan2(int* __restrict__ bsums) {
    __shared__ int s[256];
    int t = threadIdx.x;
    int v = (t < SCAN_BLOCKS) ? bsums[t] : 0;
    s[t] = v;
    __syncthreads();
    for (int off = 1; off < 256; off <<= 1) {
        int x = (t >= off) ? s[t - off] : 0;
        __syncthreads();
        s[t] += x;
        __syncthreads();
    }
    if (t < SCAN_BLOCKS) bsums[t] = s[t] - v;  // exclusive
}

__global__ __launch_bounds__(256) void k_scan3(const int* __restrict__ counts,
                                               int* __restrict__ rowst, const int* __restrict__ bsums) {
    int i = blockIdx.x * 256 + threadIdx.x;
    if (i < NN) rowst[i] = rowst[i] - counts[i] + bsums[blockIdx.x];
}

__global__ __launch_bounds__(256) void k_scatter2(const int* __restrict__ src, const int* __restrict__ dst,
                                                  const int* __restrict__ rank, const int* __restrict__ rowst,
                                                  int* __restrict__ ssrc) {
    int e = blockIdx.x * 256 + threadIdx.x;
    if (e < NE) ssrc[rowst[dst[e]] + rank[e]] = src[e];
}

// ---------- node encoder: h = x @ W + b  ([N,32]@[32,64]), also bf16 shadow ----------
__global__ __launch_bounds__(256) void k_encoder(const float* __restrict__ x, const float* __restrict__ W,
                                                 const float* __restrict__ b, float* __restrict__ h,
                                                 unsigned short* __restrict__ hbf) {
    __shared__ float Ws[INC * HH];
    __shared__ float bs[HH];
    int tid = threadIdx.x;
    for (int i = tid; i < INC * HH; i += 256) Ws[i] = W[i];
    if (tid < HH) bs[tid] = b[tid];
    __syncthreads();
    int wid = tid >> 6, lane = tid & 63;
    int n = blockIdx.x * 4 + wid;
    if (n >= NN) return;
    float v = (lane < INC) ? x[(size_t)n * INC + lane] : 0.f;
    float acc = bs[lane];
    #pragma unroll
    for (int k = 0; k < INC; ++k)
        acc += __shfl(v, k) * Ws[k * HH + lane];
    h[(size_t)n * HH + lane] = acc;
    hbf[(size_t)n * HH + lane] = f2b(acc);
}

// ---------- y = relu(LayerNorm(h)), fp32 + bf16 shadow ----------
__global__ __launch_bounds__(256) void k_lnrelu(const float* __restrict__ h, const float* __restrict__ g,
                                                const float* __restrict__ b, float* __restrict__ y,
                                                unsigned short* __restrict__ ybf) {
    int tid = threadIdx.x;
    int wid = tid >> 6, lane = tid & 63;
    int n = blockIdx.x * 4 + wid;
    if (n >= NN) return;
    float v = h[(size_t)n * HH + lane];
    float s = v;
    #pragma unroll
    for (int m = 1; m < 64; m <<= 1) s += __shfl_xor(s, m);
    float mu = s * (1.f / 64.f);
    float d = v - mu;
    float q = d * d;
    #pragma unroll
    for (int m = 1; m < 64; m <<= 1) q += __shfl_xor(q, m);
    float rs = rsqrtf(q * (1.f / 64.f) + LNE);
    float r = fmaxf(d * rs * g[lane] + b[lane], 0.f);
    y[(size_t)n * HH + lane] = r;
    ybf[(size_t)n * HH + lane] = f2b(r);
}

// ---------- per-dst softmax aggregation, dual-row gathers ----------
// Lanes 0-31 handle even edges, 32-63 odd edges; each lane loads ushort2
// (2 channels, 4B) -> one vmem instr covers 2 rows (256B). Cross-parity
// combine via shfl_xor(32), then redistribute so lane = channel.
__global__ __launch_bounds__(256) void k_agg(const float* __restrict__ y,
                                             const unsigned short* __restrict__ ybf,
                                             const int* __restrict__ rowst,
                                             const int* __restrict__ counts, const int* __restrict__ ssrc,
                                             const float* __restrict__ tp, float* __restrict__ ag) {
    int tid = threadIdx.x;
    int wid = tid >> 6, lane = tid & 63;
    int n = blockIdx.x * 4 + wid;
    if (n >= NN) return;
    float tval = *tp;
    int start = rowst[n];
    int deg = counts[n];
    float Sa = 0.f, Sma = 0.f;
    if (deg > 0 && deg <= 64) {
        int myidx = (lane < deg) ? ssrc[start + lane] : 0;
        int half = lane >> 5;      // edge parity this lane handles
        int col = lane & 31;       // channel-pair index
        float Sa0 = 0.f, Sa1 = 0.f, Sm0 = 0.f, Sm1 = 0.f;
        for (int base = 0; base < deg; base += 16) {
            float c0[8], c1[8];
            int eidx[8];
            #pragma unroll
            for (int i = 0; i < 8; ++i) {
                int e = base + 2 * i + half;
                eidx[i] = e;
                int es = (e < deg) ? e : (deg - 1);
                int s = __shfl(myidx, es);
                unsigned v = *(const unsigned*)(ybf + (size_t)s * HH + col * 2);
                c0[i] = b2f((unsigned short)(v & 0xffffu));
                c1[i] = b2f((unsigned short)(v >> 16));
            }
            #pragma unroll
            for (int i = 0; i < 8; ++i) {
                bool ok = eidx[i] < deg;
                float m0 = fmaxf(c0[i], 0.f) + MEPS;
                float m1 = fmaxf(c1[i], 0.f) + MEPS;
                float a0 = ok ? __expf(tval * m0) : 0.f;
                float a1 = ok ? __expf(tval * m1) : 0.f;
                Sa0 += a0; Sm0 += m0 * a0;
                Sa1 += a1; Sm1 += m1 * a1;
            }
        }
        Sa0 += __shfl_xor(Sa0, 32); Sa1 += __shfl_xor(Sa1, 32);
        Sm0 += __shfl_xor(Sm0, 32); Sm1 += __shfl_xor(Sm1, 32);
        // lane wants channel `lane`: pair index lane>>1, parity lane&1
        int srcl = lane >> 1;
        float saA = __shfl(Sa0, srcl), saB = __shfl(Sa1, srcl);
        float smA = __shfl(Sm0, srcl), smB = __shfl(Sm1, srcl);
        Sa = (lane & 1) ? saB : saA;
        Sma = (lane & 1) ? smB : smA;
    } else if (deg > 64) {
        for (int e = 0; e < deg; ++e) {
            int s = ssrc[start + e];
            float v = b2f(ybf[(size_t)s * HH + lane]);
            float m = fmaxf(v, 0.f) + MEPS;
            float a = __expf(tval * m);
            Sa += a; Sma += m * a;
        }
    }
    float agg = Sma / fmaxf(Sa, MEPS);  // deg==0 -> 0
    ag[(size_t)n * HH + lane] = agg + y[(size_t)n * HH + lane];
}

// ---------- GEMM A: U = ag @ W1 + b1  ([N,64]@[64,128]) ----------
__global__ __launch_bounds__(256) void k_gemmA(const float* __restrict__ A, const float* __restrict__ W,
                                               const float* __restrict__ bias, float* __restrict__ U) {
    __shared__ float As[64 * 68];
    __shared__ float Bs[HH * H2];
    __shared__ float bb[H2];
    int tid = threadIdx.x;
    int nb = blockIdx.x * 64;
    for (int i = tid; i < HH * H2 / 4; i += 256)
        ((float4*)Bs)[i] = ((const float4*)W)[i];
    if (tid < H2) bb[tid] = bias[tid];
    {
        int row = tid >> 2, cb = (tid & 3) * 16;
        int n = nb + row;
        float4* dp = (float4*)(As + row * 68 + cb);
        if (n < NN) {
            const float4* sp = (const float4*)(A + (size_t)n * HH + cb);
            #pragma unroll
            for (int i = 0; i < 4; ++i) dp[i] = sp[i];
        } else {
            float4 z = {0.f, 0.f, 0.f, 0.f};
            #pragma unroll
            for (int i = 0; i < 4; ++i) dp[i] = z;
        }
    }
    __syncthreads();
    int tx = tid & 15, ty = tid >> 4;
    int r0 = ty * 4, j0 = tx * 8;
    float acc[4][8] = {};
    #pragma unroll 8
    for (int k = 0; k < HH; ++k) {
        float4 b0 = *(const float4*)(Bs + k * H2 + j0);
        float4 b1 = *(const float4*)(Bs + k * H2 + j0 + 4);
        #pragma unroll
        for (int r = 0; r < 4; ++r) {
            float a = As[(r0 + r) * 68 + k];
            acc[r][0] += a * b0.x; acc[r][1] += a * b0.y;
            acc[r][2] += a * b0.z; acc[r][3] += a * b0.w;
            acc[r][4] += a * b1.x; acc[r][5] += a * b1.y;
            acc[r][6] += a * b1.z; acc[r][7] += a * b1.w;
        }
    }
    #pragma unroll
    for (int r = 0; r < 4; ++r) {
        int n = nb + r0 + r;
        if (n < NN) {
            float4 o0, o1;
            o0.x = acc[r][0] + bb[j0];     o0.y = acc[r][1] + bb[j0 + 1];
            o0.z = acc[r][2] + bb[j0 + 2]; o0.w = acc[r][3] + bb[j0 + 3];
            o1.x = acc[r][4] + bb[j0 + 4]; o1.y = acc[r][5] + bb[j0 + 5];
            o1.z = acc[r][6] + bb[j0 + 6]; o1.w = acc[r][7] + bb[j0 + 7];
            *(float4*)(U + (size_t)n * H2 + j0) = o0;
            *(float4*)(U + (size_t)n * H2 + j0 + 4) = o1;
        }
    }
}

// ---------- GEMM B with fused LN(128)+ReLU on input tile, +bias, +optional residual ----------
__global__ __launch_bounds__(256) void k_gemmB(const float* __restrict__ U, const float* __restrict__ W,
                                               const float* __restrict__ bias,
                                               const float* __restrict__ lng, const float* __restrict__ lnb,
                                               const float* __restrict__ hres, float* __restrict__ hout) {
    __shared__ float As[64 * 132];
    __shared__ float Bs[H2 * HH];
    __shared__ float bb[HH];
    __shared__ float lg[H2], lb[H2];
    __shared__ float ps[64 * 4], psq[64 * 4];
    __shared__ float mus[64], rss[64];
    int tid = threadIdx.x;
    int nb = blockIdx.x * 64;
    for (int i = tid; i < H2 * HH / 4; i += 256)
        ((float4*)Bs)[i] = ((const float4*)W)[i];
    if (tid < HH) bb[tid] = bias[tid];
    if (tid < H2) { lg[tid] = lng[tid]; lb[tid] = lnb[tid]; }
    {
        int row = tid >> 2, cb = (tid & 3) * 32;
        int n = nb + row;
        float4* dp = (float4*)(As + row * 132 + cb);
        if (n < NN) {
            const float4* sp = (const float4*)(U + (size_t)n * H2 + cb);
            #pragma unroll
            for (int i = 0; i < 8; ++i) dp[i] = sp[i];
        } else {
            float4 z = {0.f, 0.f, 0.f, 0.f};
            #pragma unroll
            for (int i = 0; i < 8; ++i) dp[i] = z;
        }
    }
    __syncthreads();
    {
        int row = tid >> 2, q = tid & 3;
        const float* rp = As + row * 132;
        float s = 0.f, sq = 0.f;
        #pragma unroll
        for (int i = 0; i < 32; ++i) { float v = rp[i * 4 + q]; s += v; sq += v * v; }
        ps[row * 4 + q] = s; psq[row * 4 + q] = sq;
    }
    __syncthreads();
    if (tid < 64) {
        float s = ps[tid * 4] + ps[tid * 4 + 1] + ps[tid * 4 + 2] + ps[tid * 4 + 3];
        float sq = psq[tid * 4] + psq[tid * 4 + 1] + psq[tid * 4 + 2] + psq[tid * 4 + 3];
        float mu = s * (1.f / 128.f);
        float var = sq * (1.f / 128.f) - mu * mu;
        mus[tid] = mu;
        rss[tid] = rsqrtf(fmaxf(var, 0.f) + LNE);
    }
    __syncthreads();
    {
        int row = tid >> 2, q = tid & 3;
        float mu = mus[row], rs = rss[row];
        float* rp = As + row * 132;
        #pragma unroll
        for (int i = 0; i < 32; ++i) {
            int c = i * 4 + q;
            float v = (rp[c] - mu) * rs * lg[c] + lb[c];
            rp[c] = fmaxf(v, 0.f);
        }
    }
    __syncthreads();
    int tx = tid & 15, ty = tid >> 4;
    int r0 = ty * 4, o0 = tx * 4;
    float acc[4][4] = {};
    #pragma unroll 8
    for (int k = 0; k < H2; ++k) {
        float4 b4 = *(const float4*)(Bs + k * HH + o0);
        #pragma unroll
        for (int r = 0; r < 4; ++r) {
            float a = As[(r0 + r) * 132 + k];
            acc[r][0] += a * b4.x; acc[r][1] += a * b4.y;
            acc[r][2] += a * b4.z; acc[r][3] += a * b4.w;
        }
    }
    #pragma unroll
    for (int r = 0; r < 4; ++r) {
        int n = nb + r0 + r;
        if (n < NN) {
            float4 o;
            o.x = acc[r][0] + bb[o0];     o.y = acc[r][1] + bb[o0 + 1];
            o.z = acc[r][2] + bb[o0 + 2]; o.w = acc[r][3] + bb[o0 + 3];
            if (hres) {
                float4 hr = *(const float4*)(hres + (size_t)n * HH + o0);
                o.x += hr.x; o.y += hr.y; o.z += hr.z; o.w += hr.w;
            }
            *(float4*)(hout + (size_t)n * HH + o0) = o;
        }
    }
}

// ---------- fused final LN + both heads, GEMM-tile (64 nodes/block) ----------
__global__ __launch_bounds__(256) void k_outg(const float* __restrict__ h,
                                              const float* __restrict__ lng, const float* __restrict__ lnb,
                                              const float* __restrict__ gW, const float* __restrict__ gb,
                                              const float* __restrict__ nW, const float* __restrict__ nbp,
                                              float* __restrict__ dout, unsigned* __restrict__ genc) {
    __shared__ float As[64 * 68];     // h tile, then normalized in place
    __shared__ float Wc[64 * 40];     // [k][j]: j<17 n-head, j in [17,33) g-head
    __shared__ float Os[64 * 40];     // output tile
    __shared__ float bs[40];
    __shared__ float lg[HH], lb[HH];
    __shared__ float ps[256], psq[256];
    __shared__ float mus[64], rss[64];
    int tid = threadIdx.x;
    int nb = blockIdx.x * 64;
    for (int i = tid; i < HH * ON; i += 256) { int k = i / ON, j = i - k * ON; Wc[k * 40 + j] = nW[i]; }
    for (int i = tid; i < HH * OC; i += 256) { int k = i / OC, j = i - k * OC; Wc[k * 40 + ON + j] = gW[i]; }
    if (tid < ON) bs[tid] = nbp[tid];
    else if (tid < 33) bs[tid] = gb[tid - ON];
    if (tid < HH) { lg[tid] = lng[tid]; lb[tid] = lnb[tid]; }
    {
        int row = tid >> 2, cb = (tid & 3) * 16;
        int n = nb + row;
        float4* dp = (float4*)(As + row * 68 + cb);
        if (n < NN) {
            const float4* sp = (const float4*)(h + (size_t)n * HH + cb);
            #pragma unroll
            for (int i = 0; i < 4; ++i) dp[i] = sp[i];
        } else {
            float4 z = {0.f, 0.f, 0.f, 0.f};
            #pragma unroll
            for (int i = 0; i < 4; ++i) dp[i] = z;
        }
    }
    __syncthreads();
    {
        int row = tid >> 2, q = tid & 3;
        const float* rp = As + row * 68;
        float s = 0.f, sq = 0.f;
        #pragma unroll
        for (int i = 0; i < 16; ++i) { float v = rp[q + 4 * i]; s += v; sq += v * v; }
        ps[tid] = s; psq[tid] = sq;
    }
    __syncthreads();
    if (tid < 64) {
        float s = ps[tid * 4] + ps[tid * 4 + 1] + ps[tid * 4 + 2] + ps[tid * 4 + 3];
        float sq = psq[tid * 4] + psq[tid * 4 + 1] + psq[tid * 4 + 2] + psq[tid * 4 + 3];
        float mu = s * (1.f / 64.f);
        float var = sq * (1.f / 64.f) - mu * mu;
        mus[tid] = mu;
        rss[tid] = rsqrtf(fmaxf(var, 0.f) + LNE);
    }
    __syncthreads();
    {
        int row = tid >> 2, q = tid & 3;
        float mu = mus[row], rs = rss[row];
        float* rp = As + row * 68;
        #pragma unroll
        for (int i = 0; i < 16; ++i) {
            int c = q + 4 * i;
            rp[c] = fmaxf((rp[c] - mu) * rs * lg[c] + lb[c], 0.f);
        }
    }
    __syncthreads();
    int tx = tid & 15, ty = tid >> 4;
    int r0 = ty * 4;
    float acc[4][3];
    #pragma unroll
    for (int r = 0; r < 4; ++r) {
        acc[r][0] = bs[tx]; acc[r][1] = bs[tx + 16]; acc[r][2] = bs[32];
    }
    #pragma unroll 4
    for (int k = 0; k < HH; ++k) {
        float w0 = Wc[k * 40 + tx];
        float w1 = Wc[k * 40 + 16 + tx];
        float w2 = Wc[k * 40 + 32];
        #pragma unroll
        for (int r = 0; r < 4; ++r) {
            float a = As[(r0 + r) * 68 + k];
            acc[r][0] += a * w0; acc[r][1] += a * w1; acc[r][2] += a * w2;
        }
    }
    #pragma unroll
    for (int r = 0; r < 4; ++r) {
        Os[(r0 + r) * 40 + tx] = acc[r][0];
        Os[(r0 + r) * 40 + 16 + tx] = acc[r][1];
        if (tx == 0) Os[(r0 + r) * 40 + 32] = acc[r][2];
    }
    __syncthreads();
    // n-head store: linear index is exactly row-major [n][17] -> coalesced
    for (int i = tid; i < 64 * ON; i += 256) {
        int r = i / ON, j = i - r * ON;
        int n = nb + r;
        if (n < NN) dout[OC + (size_t)n * ON + j] = Os[r * 40 + j];
    }
    // g-head block max
    if (tid < OC) {
        int rmax = NN - nb; if (rmax > 64) rmax = 64;
        float m = -INFINITY;
        for (int r = 0; r < rmax; ++r) m = fmaxf(m, Os[r * 40 + ON + tid]);
        atomicMax(&genc[tid], fenc(m));
    }
}

__global__ void k_gdec(const unsigned* __restrict__ genc, float* __restrict__ dout) {
    int t = threadIdx.x;
    if (t < OC) dout[t] = fdec(genc[t]);
}

// ---------- launch ----------
extern "C" void kernel_launch(void* const* d_in, const int* in_sizes, int n_in,
                              void* d_out, int out_size, void* d_ws, size_t ws_size,
                              hipStream_t stream) {
    const float* x     = (const float*)d_in[0];
    const float* nodeW = (const float*)d_in[1];
    const float* nodeB = (const float*)d_in[2];
    const float* W1    = (const float*)d_in[3];
    const float* b1    = (const float*)d_in[4];
    const float* mlg   = (const float*)d_in[5];
    const float* mlb   = (const float*)d_in[6];
    const float* W2    = (const float*)d_in[7];
    const float* b2    = (const float*)d_in[8];
    const float* tt    = (const float*)d_in[9];
    const float* lng   = (const float*)d_in[10];
    const float* lnb   = (const float*)d_in[11];
    const int*   ei    = (const int*)d_in[12];
    const float* gW    = (const float*)d_in[13];
    const float* gb    = (const float*)d_in[14];
    const float* nW    = (const float*)d_in[15];
    const float* nbp   = (const float*)d_in[16];
    float* out = (float*)d_out;

    char* ws = (char*)d_ws;
    size_t off = 0;
    auto alloc = [&](size_t bytes) -> void* {
        void* p = ws + off;
        off = (off + bytes + 255) & ~(size_t)255;
        return p;
    };
    int* counts    = (int*)alloc((size_t)NN * 4);
    unsigned* genc = (unsigned*)alloc(64);
    size_t zero_end = off;
    int* bsums = (int*)alloc(1024);
    int* rowst = (int*)alloc((size_t)NN * 4);
    int* ssrc  = (int*)alloc((size_t)NE * 4);
    float* h   = (float*)alloc((size_t)NN * HH * 4);
    float* y   = (float*)alloc((size_t)NN * HH * 4);
    float* ag  = (float*)alloc((size_t)NN * HH * 4);
    float* u   = (float*)alloc((size_t)NN * H2 * 4);
    unsigned short* ybf = (unsigned short*)alloc((size_t)NN * HH * 2);
    int* rank = (int*)u;   // alias: rank only lives during CSR build, u only during layers

    const int* esrc = ei;
    const int* edst = ei + NE;

    hipMemsetAsync(d_ws, 0, zero_end, stream);

    k_hist2<<<(NE + 255) / 256, 256, 0, stream>>>(edst, counts, rank);
    k_scan1<<<SCAN_BLOCKS, 256, 0, stream>>>(counts, rowst, bsums);
    k_scan2<<<1, 256, 0, stream>>>(bsums);
    k_scan3<<<SCAN_BLOCKS, 256, 0, stream>>>(counts, rowst, bsums);
    k_scatter2<<<(NE + 255) / 256, 256, 0, stream>>>(esrc, edst, rank, rowst, ssrc);
    k_encoder<<<(NN + 3) / 4, 256, 0, stream>>>(x, nodeW, nodeB, h, ybf);

    for (int l = 0; l < NL; ++l) {
        const float* yin = h;
        if (l > 0) {
            k_lnrelu<<<(NN + 3) / 4, 256, 0, stream>>>(h, lng + l * HH, lnb + l * HH, y, ybf);
            yin = y;
        }
        k_agg<<<(NN + 3) / 4, 256, 0, stream>>>(yin, ybf, rowst, counts, ssrc, tt + l, ag);
        k_gemmA<<<(NN + 63) / 64, 256, 0, stream>>>(ag, W1 + (size_t)l * HH * H2, b1 + (size_t)l * H2, u);
        k_gemmB<<<(NN + 63) / 64, 256, 0, stream>>>(u, W2 + (size_t)l * H2 * HH, b2 + (size_t)l * HH,
                                                    mlg + (size_t)l * H2, mlb + (size_t)l * H2,
                                                    (l == 0) ? (const float*)nullptr : h, h);
    }
    k_outg<<<(NN + 63) / 64, 256, 0, stream>>>(h, lng, lnb, gW, gb, nW, nbp, out, genc);
    k_gdec<<<1, 64, 0, stream>>>(genc, out);
}